// Round 8
// baseline (354.496 us; speedup 1.0000x reference)
//
#include <hip/hip_runtime.h>

#define NN 50000
#define NE 800000
#define DIM 128
#define NB 128          // dst buckets for binned slot build
#define CH 4096         // edges per binning block
#define CAP 8192        // slots per bucket (mean 6250, sd 79 -> +24 sigma)
#define MAXDEG 64       // per-(set,dst) slot row; P(deg>64)~1e-21 for Poisson(16)
#define BPSET ((NE + CH - 1) / CH)
#define NBIN_BLOCKS (4 * BPSET)

typedef unsigned int uint;
typedef unsigned short ushort;
typedef __attribute__((ext_vector_type(8))) short v8s;
typedef __attribute__((ext_vector_type(4))) float v4f;

__device__ __forceinline__ ushort f2bf(float f) {
    union { float f; uint i; } c; c.f = f;
    const uint r = (c.i + 0x7fffu + ((c.i >> 16) & 1u)) >> 16;
    return (ushort)r;
}

// ---------------- WT transpose body ----------------
// WT[m][n][k] = bf16(W[m][k][n]); m: 0,1 from W0, 2,3 from W1.
__device__ __forceinline__ void conv_body(
    const float* __restrict__ W0, const float* __restrict__ W1,
    ushort* __restrict__ WT, int bid)
{
    const int t = bid * 256 + threadIdx.x;
#pragma unroll
    for (int i = 0; i < 4; i++) {
        const int o = t * 4 + i;                    // 0 .. 65535
        const int m = o >> 14, rem = o & 16383;
        const int nrow = rem >> 7, k = rem & 127;
        const float* src = (m < 2) ? (W0 + (size_t)m * 16384)
                                   : (W1 + (size_t)(m - 2) * 16384);
        WT[o] = f2bf(src[k * 128 + nrow]);
    }
}

// ---------------- dual-relation MFMA GEMM body ----------------
// Block 256 = 4 waves; wave w: rows [b*64+16w,+16) x 128 cols, both relations.
// A loaded once (f32 path converts in-register). Epilogue: LDS-staged
// coalesced bf16 store + fused el/er reduction.
__device__ __forceinline__ void gemm_body(
    ushort (*tile)[136],
    const ushort* __restrict__ hbf, const float* __restrict__ xf,
    const ushort* __restrict__ WT,
    const float* __restrict__ al, const float* __restrict__ ar,
    ushort* __restrict__ fg0, ushort* __restrict__ fg1,
    float* __restrict__ elb, int n, int is_f32, int bid)
{
    const int tid = threadIdx.x;
    const int w = tid >> 6, lane = tid & 63;
    const int quad = lane >> 4, l16 = lane & 15;
    const int row0 = bid * 64 + w * 16;

    int arow = row0 + l16;
    if (arow >= n) arow = n - 1;   // clamp; OOB rows never stored

    v8s afr[4];
    if (is_f32) {
        const float* ap = xf + (size_t)arow * DIM + quad * 8;
#pragma unroll
        for (int kt = 0; kt < 4; kt++) {
            const float4 a0 = *(const float4*)(ap + kt * 32);
            const float4 a1 = *(const float4*)(ap + kt * 32 + 4);
            ushort tmp[8] = { f2bf(a0.x), f2bf(a0.y), f2bf(a0.z), f2bf(a0.w),
                              f2bf(a1.x), f2bf(a1.y), f2bf(a1.z), f2bf(a1.w) };
            afr[kt] = *(const v8s*)tmp;
        }
    } else {
        const ushort* ap = hbf + (size_t)arow * DIM + quad * 8;
#pragma unroll
        for (int kt = 0; kt < 4; kt++) afr[kt] = *(const v8s*)(ap + kt * 32);
    }

    for (int rel = 0; rel < 2; rel++) {
        const ushort* bp = WT + (size_t)rel * DIM * DIM + (size_t)l16 * DIM + quad * 8;
        v4f acc[8];
#pragma unroll
        for (int nt = 0; nt < 8; nt++) acc[nt] = (v4f)0.0f;
#pragma unroll
        for (int kt = 0; kt < 4; kt++) {
#pragma unroll
            for (int nt = 0; nt < 8; nt++) {
                const v8s b = *(const v8s*)(bp + (size_t)nt * 16 * DIM + kt * 32);
                acc[nt] = __builtin_amdgcn_mfma_f32_16x16x32_bf16(afr[kt], b, acc[nt], 0, 0, 0);
            }
        }

        // el/er: partial dot per lane, reduce across l16 within quad rows
        const float* alr = al + rel * DIM;
        const float* arr = ar + rel * DIM;
        float pel[4][2], per2[4][2];
#pragma unroll
        for (int r = 0; r < 4; r++)
            pel[r][0] = pel[r][1] = per2[r][0] = per2[r][1] = 0.f;
#pragma unroll
        for (int nt = 0; nt < 8; nt++) {
            const int col = nt * 16 + l16;
            const float av = alr[col], rv = arr[col];
            const int head = nt >> 2;
#pragma unroll
            for (int r = 0; r < 4; r++) {
                pel[r][head] += acc[nt][r] * av;
                per2[r][head] += acc[nt][r] * rv;
            }
        }
#pragma unroll
        for (int o = 1; o < 16; o <<= 1) {
#pragma unroll
            for (int r = 0; r < 4; r++) {
#pragma unroll
                for (int h = 0; h < 2; h++) {
                    pel[r][h] += __shfl_xor(pel[r][h], o);
                    per2[r][h] += __shfl_xor(per2[r][h], o);
                }
            }
        }
        float* elp = elb + (size_t)rel * NN * 4;
        float* erp = elp + (size_t)NN * 2;
        if (l16 == 0) {
#pragma unroll
            for (int r = 0; r < 4; r++) {
                const int row = row0 + quad * 4 + r;
                if (row < n) {
#pragma unroll
                    for (int h = 0; h < 2; h++) {
                        elp[row * 2 + h] = pel[r][h];
                        erp[row * 2 + h] = per2[r][h];
                    }
                }
            }
        }

        // coalesced bf16 store via LDS
        __syncthreads();   // prior rel's tile reads done
        const int lr0 = w * 16 + quad * 4;
#pragma unroll
        for (int nt = 0; nt < 8; nt++) {
            const int col = nt * 16 + l16;
#pragma unroll
            for (int r = 0; r < 4; r++)
                tile[lr0 + r][col] = f2bf(acc[nt][r]);
        }
        __syncthreads();
        ushort* fgr = rel ? fg1 : fg0;
        const int srow = tid >> 2, ch = tid & 3;   // 64 rows x 4 chunks of 32
        const int grow = bid * 64 + srow;
        if (grow < n) {
            const uint4* lp = (const uint4*)&tile[srow][ch * 32];
            uint4* gp = (uint4*)(fgr + (size_t)grow * DIM + ch * 32);
            gp[0] = lp[0];
            gp[1] = lp[1];
            gp[2] = lp[2];
            gp[3] = lp[3];
        }
    }
}

__global__ __launch_bounds__(256) void gemm_dual(
    const ushort* __restrict__ hbf, const float* __restrict__ xf,
    const ushort* __restrict__ WT,
    const float* __restrict__ al, const float* __restrict__ ar,
    ushort* __restrict__ fg0, ushort* __restrict__ fg1,
    float* __restrict__ elb, int n, int is_f32)
{
    __shared__ ushort tile[64][136];
    gemm_body(tile, hbf, xf, WT, al, ar, fg0, fg1, elb, n, is_f32, blockIdx.x);
}

// Pass A body: bin edges by dst bucket; payload packed (dst<<16)|src.
// gcur is a zero-initialized per-bucket fill counter; binned slot offsets are
// absolute ((s*NB+b)*CAP + fill).
__device__ __forceinline__ void bin_body(
    char* smem,
    const int* __restrict__ dst0, const int* __restrict__ dst1,
    const int* __restrict__ src0, const int* __restrict__ src1,
    int* __restrict__ gcur, uint* __restrict__ binned, int bid)
{
    int* hist  = (int*)smem;
    int* ebase = hist + NB;
    int* lcur  = ebase + NB;
    int* gbase = lcur + NB;
    int* sc    = gbase + NB;
    uint* stage = (uint*)(sc + NB);   // CH entries

    const int s = bid / BPSET, cb = bid - s * BPSET;
    const int* dstp = (s < 2) ? (dst0 + (size_t)s * NE) : (dst1 + (size_t)(s - 2) * NE);
    const int* srcp = (s < 2) ? (src0 + (size_t)s * NE) : (src1 + (size_t)(s - 2) * NE);
    const int e0 = cb * CH;
    const int t = threadIdx.x;

    if (t < NB) hist[t] = 0;
    __syncthreads();

    int myd[16], mys[16];
#pragma unroll
    for (int k = 0; k < 16; k++) {
        const int e = e0 + t + k * 256;
        if (e < NE) {
            const int d = dstp[e];
            myd[k] = d;
            mys[k] = srcp[e];
            atomicAdd(&hist[(d * NB) / NN], 1);
        } else myd[k] = -1;
    }
    __syncthreads();
    if (t < NB) sc[t] = hist[t];
    __syncthreads();
    for (int o = 1; o < NB; o <<= 1) {
        int tv = 0;
        if (t < NB && t >= o) tv = sc[t - o];
        __syncthreads();
        if (t < NB) sc[t] += tv;
        __syncthreads();
    }
    if (t < NB) {
        ebase[t] = sc[t] - hist[t];
        lcur[t]  = sc[t] - hist[t];
        gbase[t] = (s * NB + t) * CAP + atomicAdd(&gcur[s * NB + t], hist[t]);
    }
    __syncthreads();
#pragma unroll
    for (int k = 0; k < 16; k++) {
        if (myd[k] >= 0) {
            const int b = (myd[k] * NB) / NN;
            const int p = atomicAdd(&lcur[b], 1);
            stage[p] = ((uint)myd[k] << 16) | (uint)mys[k];
        }
    }
    __syncthreads();
    const int total = ebase[NB - 1] + hist[NB - 1];
    for (int i = t; i < total; i += 256) {
        const uint v = stage[i];
        const int b = ((int)(v >> 16) * NB) / NN;
        binned[gbase[b] + (i - ebase[b])] = v;   // absolute slot offset
    }
}

// ---------------- launch A: conv_wt blocks || bin_edges blocks --------------
__global__ __launch_bounds__(256) void prep_a(
    const float* __restrict__ W0, const float* __restrict__ W1,
    ushort* __restrict__ WT,
    const int* __restrict__ dst0, const int* __restrict__ dst1,
    const int* __restrict__ src0, const int* __restrict__ src1,
    int* __restrict__ gcur, uint* __restrict__ binned)
{
    __shared__ __align__(16) char smem[18944];
    const int bid = blockIdx.x;
    if (bid < 64) {
        conv_body(W0, W1, WT, bid);
    } else {
        bin_body(smem, dst0, dst1, src0, src1, gcur, binned, bid - 64);
    }
}

// Pass B body: per (set,bucket): direct scatter into padded 64-slot rows.
// All writes land in this block's private 50KB window -> L2-local, no
// cross-XCD line bouncing (R5's failure mode), no scans, no row[] array.
__device__ __forceinline__ void slot_body(
    int* lcur, const int* __restrict__ gcur, const uint* __restrict__ binned,
    int* __restrict__ cnt, ushort* __restrict__ slots, int bid)
{
    const int s = bid >> 7, b = bid & (NB - 1);
    const int nb0 = (b * NN + NB - 1) / NB;
    int nb1 = ((b + 1) * NN + NB - 1) / NB;
    if (nb1 > NN) nb1 = NN;
    const int nloc = nb1 - nb0;
    int fill = gcur[s * NB + b];
    if (fill > CAP) fill = CAP;
    const uint* bslot = binned + (size_t)(s * NB + b) * CAP;
    const int t = threadIdx.x;

    for (int i = t; i < nloc; i += 256) lcur[i] = 0;
    __syncthreads();
    ushort* sbase = slots + (size_t)s * NN * MAXDEG;
    for (int j = t; j < fill; j += 256) {
        const uint v = bslot[j];
        const int d = (int)(v >> 16);
        const int p = atomicAdd(&lcur[d - nb0], 1);
        if (p < MAXDEG) sbase[(size_t)d * MAXDEG + p] = (ushort)(v & 0xffffu);
    }
    __syncthreads();
    for (int i = t; i < nloc; i += 256) {
        const int c = lcur[i];
        cnt[s * NN + nb0 + i] = c < MAXDEG ? c : MAXDEG;
    }
}

// ---------------- launch B: gemm layer-0 blocks || slot-build blocks --------
__global__ __launch_bounds__(256) void prep_b(
    const float* __restrict__ xf, const ushort* __restrict__ WT,
    const float* __restrict__ al, const float* __restrict__ ar,
    ushort* __restrict__ fg0, ushort* __restrict__ fg1,
    float* __restrict__ elb,
    const int* __restrict__ gcur, const uint* __restrict__ binned,
    int* __restrict__ cnt, ushort* __restrict__ slots, int gblocks)
{
    __shared__ __align__(16) char smem[17408];  // max(gemm tile 17408, lcur 1568)
    const int bid = blockIdx.x;
    if (bid < gblocks) {
        gemm_body((ushort(*)[136])smem, nullptr, xf, WT, al, ar,
                  fg0, fg1, elb, NN, 1, bid);
    } else {
        slot_body((int*)smem, gcur, binned, cnt, slots, bid - gblocks);
    }
}

__device__ __forceinline__ float elu(float v) { return v > 0.f ? v : expm1f(v); }
__device__ __forceinline__ float2 bfpair(uint u) {
    union { uint i; float f; } lo, hi;
    lo.i = u << 16;
    hi.i = u & 0xffff0000u;
    return make_float2(lo.f, hi.f);
}

// ---------------- single-relation fused softmax + aggregate ----------------
// Split by RELATION (locality-neutral: each rel gathers from its own fg
// array) so each dispatch is ~35us -> the mid-tier kernels become visible in
// the profile. Phase 0 writes f32 partial elu(acc+b); phase 1 adds its rel's
// elu and writes the final output. Partial is L2/L3-resident (25.6MB); block
// i handles the same nodes in both phases -> mostly L2-hit readback.
// 16-deep unrolled gather pipeline (measured sweet spot at VGPR ~32).
__global__ __launch_bounds__(256) void aggregate_rel(
    const int* __restrict__ cnt, const ushort* __restrict__ sl,
    const float2* __restrict__ el, const float2* __restrict__ er,
    const ushort* __restrict__ fg, const float* __restrict__ bias,
    float2* __restrict__ part,
    float* __restrict__ outf, ushort* __restrict__ outbf,
    int phase, int obf)
{
    __shared__ uint soff[4][64];
    __shared__ float wts[4][2][64];
    const int wv = (blockIdx.x * 256 + threadIdx.x) >> 6;
    if (wv >= NN) return;
    const int lane = threadIdx.x & 63;
    const int wid = threadIdx.x >> 6;

    const int deg = cnt[wv];           // <= MAXDEG guaranteed by slot build
    const float2 erd = er[wv];
    float2 acc = make_float2(0.f, 0.f);

    uint sof = 0;
    float ex0 = 0.f, ex1 = 0.f;
    if (lane < deg) {
        const int s = sl[(size_t)wv * MAXDEG + lane];
        const float2 e = el[s];
        float e0 = e.x + erd.x, e1 = e.y + erd.y;
        e0 = e0 > 0.f ? e0 : 0.2f * e0;
        e1 = e1 > 0.f ? e1 : 0.2f * e1;
        ex0 = __expf(e0);
        ex1 = __expf(e1);
        sof = (uint)s << 8;
    }
    float den0 = ex0, den1 = ex1;
    for (int o = 32; o > 0; o >>= 1) {
        den0 += __shfl_xor(den0, o);
        den1 += __shfl_xor(den1, o);
    }
    const float inv0 = 1.0f / den0, inv1 = 1.0f / den1;
    soff[wid][lane] = sof;
    wts[wid][0][lane] = ex0 * inv0;   // 0 for lane >= deg
    wts[wid][1][lane] = ex1 * inv1;
    const char* fgb = (const char*)fg + lane * 4;
    const float* wrow = wts[wid][lane >> 5];
    const uint* sorow = soff[wid];
    const int dp = (deg + 15) & ~15;   // pad slots: w=0, sof=0 (row 0)
    for (int tt = 0; tt < dp; tt += 16) {
        uint off[16];
        float wgt[16];
#pragma unroll
        for (int k = 0; k < 16; k++) {
            off[k] = sorow[tt + k];
            wgt[k] = wrow[tt + k];
        }
        uint u[16];
#pragma unroll
        for (int k = 0; k < 16; k++)
            u[k] = *(const uint*)(fgb + off[k]);
#pragma unroll
        for (int k = 0; k < 16; k++) {
            const float2 f = bfpair(u[k]);
            acc.x += f.x * wgt[k];
            acc.y += f.y * wgt[k];
        }
    }

    const float b0 = bias[2 * lane], b1 = bias[2 * lane + 1];
    float o0 = elu(acc.x + b0);
    float o1 = elu(acc.y + b1);

    if (phase == 0) {
        part[(size_t)wv * 64 + lane] = make_float2(o0, o1);
    } else {
        const float2 p = part[(size_t)wv * 64 + lane];
        o0 += p.x;
        o1 += p.y;
        if (obf) {
            ushort tmp[2] = { f2bf(o0), f2bf(o1) };
            *(uint*)(outbf + (size_t)wv * DIM + 2 * lane) = *(const uint*)tmp;
        } else {
            float* op = outf + (size_t)wv * DIM + 2 * lane;
            op[0] = o0; op[1] = o1;
        }
    }
}

extern "C" void kernel_launch(void* const* d_in, const int* in_sizes, int n_in,
                              void* d_out, int out_size, void* d_ws, size_t ws_size,
                              hipStream_t stream)
{
    const float* x   = (const float*)d_in[0];
    const float* W0  = (const float*)d_in[1];
    const float* al0 = (const float*)d_in[2];
    const float* ar0 = (const float*)d_in[3];
    const float* b0  = (const float*)d_in[4];
    const float* W1  = (const float*)d_in[5];
    const float* al1 = (const float*)d_in[6];
    const float* ar1 = (const float*)d_in[7];
    const float* b1  = (const float*)d_in[8];
    const int* src0 = (const int*)d_in[9];
    const int* dst0 = (const int*)d_in[10];
    const int* src1 = (const int*)d_in[11];
    const int* dst1 = (const int*)d_in[12];
    float* out = (float*)d_out;

    char* w = (char*)d_ws;
    auto alloc = [&](size_t bytes) {
        char* p = w; w += (bytes + 255) & ~(size_t)255; return p;
    };
    ushort* h1bf   = (ushort*)alloc((size_t)NN * DIM * 2);
    ushort* fg0    = (ushort*)alloc((size_t)NN * DIM * 2);
    ushort* fg1    = (ushort*)alloc((size_t)NN * DIM * 2);
    ushort* WT     = (ushort*)alloc((size_t)4 * DIM * DIM * 2);
    float*  elb    = (float*)alloc((size_t)8 * NN * 4);      // el0,er0,el1,er1
    int*    cnt    = (int*)alloc((size_t)4 * NN * 4);
    ushort* slots  = (ushort*)alloc((size_t)4 * NN * MAXDEG * 2);
    uint*   binned = (uint*)alloc((size_t)4 * NB * CAP * 4); // slotted
    int*    gcur   = (int*)alloc((size_t)4 * NB * 4);
    float2* part   = (float2*)alloc((size_t)NN * 64 * 8);    // f32 rel partial

    const int gblocks = (NN + 63) / 64;
    const int ablocks = (NN * 64 + 255) / 256;

    // ---- prep ----
    hipMemsetAsync(gcur, 0, (size_t)4 * NB * 4, stream);
    // conv_wt (64 blocks) || bin_edges (784 blocks)
    prep_a<<<64 + NBIN_BLOCKS, 256, 0, stream>>>(
        W0, W1, WT, dst0, dst1, src0, src1, gcur, binned);
    // gemm layer-0 (782 blocks) || slot build (512 blocks)
    prep_b<<<gblocks + 4 * NB, 256, 0, stream>>>(
        x, WT, al0, ar0, fg0, fg1, elb, gcur, binned, cnt, slots, gblocks);

    for (int L = 0; L < 2; L++) {
        if (L) {
            gemm_dual<<<gblocks, 256, 0, stream>>>(
                h1bf, nullptr, WT + (size_t)2 * DIM * DIM, al1, ar1,
                fg0, fg1, elb, NN, 0);
        }
        const float* b = L ? b1 : b0;
        const int es0 = L * 2, es1 = L * 2 + 1;
        float* el0p = elb;
        float* er0p = elb + (size_t)NN * 2;
        float* el1p = elb + (size_t)NN * 4;
        float* er1p = elb + (size_t)NN * 6;
        aggregate_rel<<<ablocks, 256, 0, stream>>>(
            cnt + (size_t)es0 * NN, slots + (size_t)es0 * NN * MAXDEG,
            (const float2*)el0p, (const float2*)er0p,
            fg0, b, part, nullptr, nullptr, 0, 0);
        aggregate_rel<<<ablocks, 256, 0, stream>>>(
            cnt + (size_t)es1 * NN, slots + (size_t)es1 * NN * MAXDEG,
            (const float2*)el1p, (const float2*)er1p,
            fg1, b + DIM, part,
            L ? out : nullptr, L ? nullptr : h1bf, 1, L ? 0 : 1);
    }
}

// Round 9
// 349.170 us; speedup vs baseline: 1.0153x; 1.0153x over previous
//
#include <hip/hip_runtime.h>

#define NN 50000
#define NE 800000
#define DIM 128
#define NB 128          // dst buckets for binned slot build
#define CH 4096         // edges per binning block
#define CAP 8192        // slots per bucket (mean 6250, sd 79 -> +24 sigma)
#define MAXDEG 64       // per-(set,dst) slot row; P(deg>64)~1e-21 for Poisson(16)
#define WINMAX 391      // max nodes per bucket window: ceil(NN/NB)
#define BPSET ((NE + CH - 1) / CH)
#define NBIN_BLOCKS (4 * BPSET)

typedef unsigned int uint;
typedef unsigned short ushort;
typedef __attribute__((ext_vector_type(8))) short v8s;
typedef __attribute__((ext_vector_type(4))) float v4f;

__device__ __forceinline__ ushort f2bf(float f) {
    union { float f; uint i; } c; c.f = f;
    const uint r = (c.i + 0x7fffu + ((c.i >> 16) & 1u)) >> 16;
    return (ushort)r;
}

// ---------------- WT transpose body ----------------
// WT[m][n][k] = bf16(W[m][k][n]); m: 0,1 from W0, 2,3 from W1.
__device__ __forceinline__ void conv_body(
    const float* __restrict__ W0, const float* __restrict__ W1,
    ushort* __restrict__ WT, int bid)
{
    const int t = bid * 256 + threadIdx.x;
#pragma unroll
    for (int i = 0; i < 4; i++) {
        const int o = t * 4 + i;                    // 0 .. 65535
        const int m = o >> 14, rem = o & 16383;
        const int nrow = rem >> 7, k = rem & 127;
        const float* src = (m < 2) ? (W0 + (size_t)m * 16384)
                                   : (W1 + (size_t)(m - 2) * 16384);
        WT[o] = f2bf(src[k * 128 + nrow]);
    }
}

// ---------------- dual-relation MFMA GEMM ----------------
// Block 256 = 4 waves; wave w: rows [b*64+16w,+16) x 128 cols, both relations.
// A loaded once (f32 path converts in-register). Epilogue: LDS-staged
// coalesced bf16 store + fused el/er reduction.
__global__ __launch_bounds__(256) void gemm_dual(
    const ushort* __restrict__ hbf, const float* __restrict__ xf,
    const ushort* __restrict__ WT,
    const float* __restrict__ al, const float* __restrict__ ar,
    ushort* __restrict__ fg0, ushort* __restrict__ fg1,
    float* __restrict__ elb, int n, int is_f32)
{
    __shared__ ushort tile[64][136];
    const int tid = threadIdx.x;
    const int w = tid >> 6, lane = tid & 63;
    const int quad = lane >> 4, l16 = lane & 15;
    const int row0 = blockIdx.x * 64 + w * 16;

    int arow = row0 + l16;
    if (arow >= n) arow = n - 1;   // clamp; OOB rows never stored

    v8s afr[4];
    if (is_f32) {
        const float* ap = xf + (size_t)arow * DIM + quad * 8;
#pragma unroll
        for (int kt = 0; kt < 4; kt++) {
            const float4 a0 = *(const float4*)(ap + kt * 32);
            const float4 a1 = *(const float4*)(ap + kt * 32 + 4);
            ushort tmp[8] = { f2bf(a0.x), f2bf(a0.y), f2bf(a0.z), f2bf(a0.w),
                              f2bf(a1.x), f2bf(a1.y), f2bf(a1.z), f2bf(a1.w) };
            afr[kt] = *(const v8s*)tmp;
        }
    } else {
        const ushort* ap = hbf + (size_t)arow * DIM + quad * 8;
#pragma unroll
        for (int kt = 0; kt < 4; kt++) afr[kt] = *(const v8s*)(ap + kt * 32);
    }

    for (int rel = 0; rel < 2; rel++) {
        const ushort* bp = WT + (size_t)rel * DIM * DIM + (size_t)l16 * DIM + quad * 8;
        v4f acc[8];
#pragma unroll
        for (int nt = 0; nt < 8; nt++) acc[nt] = (v4f)0.0f;
#pragma unroll
        for (int kt = 0; kt < 4; kt++) {
#pragma unroll
            for (int nt = 0; nt < 8; nt++) {
                const v8s b = *(const v8s*)(bp + (size_t)nt * 16 * DIM + kt * 32);
                acc[nt] = __builtin_amdgcn_mfma_f32_16x16x32_bf16(afr[kt], b, acc[nt], 0, 0, 0);
            }
        }

        // el/er: partial dot per lane, reduce across l16 within quad rows
        const float* alr = al + rel * DIM;
        const float* arr = ar + rel * DIM;
        float pel[4][2], per2[4][2];
#pragma unroll
        for (int r = 0; r < 4; r++)
            pel[r][0] = pel[r][1] = per2[r][0] = per2[r][1] = 0.f;
#pragma unroll
        for (int nt = 0; nt < 8; nt++) {
            const int col = nt * 16 + l16;
            const float av = alr[col], rv = arr[col];
            const int head = nt >> 2;
#pragma unroll
            for (int r = 0; r < 4; r++) {
                pel[r][head] += acc[nt][r] * av;
                per2[r][head] += acc[nt][r] * rv;
            }
        }
#pragma unroll
        for (int o = 1; o < 16; o <<= 1) {
#pragma unroll
            for (int r = 0; r < 4; r++) {
#pragma unroll
                for (int h = 0; h < 2; h++) {
                    pel[r][h] += __shfl_xor(pel[r][h], o);
                    per2[r][h] += __shfl_xor(per2[r][h], o);
                }
            }
        }
        float* elp = elb + (size_t)rel * NN * 4;
        float* erp = elp + (size_t)NN * 2;
        if (l16 == 0) {
#pragma unroll
            for (int r = 0; r < 4; r++) {
                const int row = row0 + quad * 4 + r;
                if (row < n) {
#pragma unroll
                    for (int h = 0; h < 2; h++) {
                        elp[row * 2 + h] = pel[r][h];
                        erp[row * 2 + h] = per2[r][h];
                    }
                }
            }
        }

        // coalesced bf16 store via LDS
        __syncthreads();   // prior rel's tile reads done
        const int lr0 = w * 16 + quad * 4;
#pragma unroll
        for (int nt = 0; nt < 8; nt++) {
            const int col = nt * 16 + l16;
#pragma unroll
            for (int r = 0; r < 4; r++)
                tile[lr0 + r][col] = f2bf(acc[nt][r]);
        }
        __syncthreads();
        ushort* fgr = rel ? fg1 : fg0;
        const int srow = tid >> 2, ch = tid & 3;   // 64 rows x 4 chunks of 32
        const int grow = blockIdx.x * 64 + srow;
        if (grow < n) {
            const uint4* lp = (const uint4*)&tile[srow][ch * 32];
            uint4* gp = (uint4*)(fgr + (size_t)grow * DIM + ch * 32);
            gp[0] = lp[0];
            gp[1] = lp[1];
            gp[2] = lp[2];
            gp[3] = lp[3];
        }
    }
}

// Pass A body: bin edges by dst bucket; payload packed (dst<<16)|src.
// gcur is a zero-initialized per-bucket fill counter; binned slot offsets are
// absolute ((s*NB+b)*CAP + fill).
__device__ __forceinline__ void bin_body(
    char* smem,
    const int* __restrict__ dst0, const int* __restrict__ dst1,
    const int* __restrict__ src0, const int* __restrict__ src1,
    int* __restrict__ gcur, uint* __restrict__ binned, int bid)
{
    int* hist  = (int*)smem;
    int* ebase = hist + NB;
    int* lcur  = ebase + NB;
    int* gbase = lcur + NB;
    int* sc    = gbase + NB;
    uint* stage = (uint*)(sc + NB);   // CH entries

    const int s = bid / BPSET, cb = bid - s * BPSET;
    const int* dstp = (s < 2) ? (dst0 + (size_t)s * NE) : (dst1 + (size_t)(s - 2) * NE);
    const int* srcp = (s < 2) ? (src0 + (size_t)s * NE) : (src1 + (size_t)(s - 2) * NE);
    const int e0 = cb * CH;
    const int t = threadIdx.x;

    if (t < NB) hist[t] = 0;
    __syncthreads();

    int myd[16], mys[16];
#pragma unroll
    for (int k = 0; k < 16; k++) {
        const int e = e0 + t + k * 256;
        if (e < NE) {
            const int d = dstp[e];
            myd[k] = d;
            mys[k] = srcp[e];
            atomicAdd(&hist[(d * NB) / NN], 1);
        } else myd[k] = -1;
    }
    __syncthreads();
    if (t < NB) sc[t] = hist[t];
    __syncthreads();
    for (int o = 1; o < NB; o <<= 1) {
        int tv = 0;
        if (t < NB && t >= o) tv = sc[t - o];
        __syncthreads();
        if (t < NB) sc[t] += tv;
        __syncthreads();
    }
    if (t < NB) {
        ebase[t] = sc[t] - hist[t];
        lcur[t]  = sc[t] - hist[t];
        gbase[t] = (s * NB + t) * CAP + atomicAdd(&gcur[s * NB + t], hist[t]);
    }
    __syncthreads();
#pragma unroll
    for (int k = 0; k < 16; k++) {
        if (myd[k] >= 0) {
            const int b = (myd[k] * NB) / NN;
            const int p = atomicAdd(&lcur[b], 1);
            stage[p] = ((uint)myd[k] << 16) | (uint)mys[k];
        }
    }
    __syncthreads();
    const int total = ebase[NB - 1] + hist[NB - 1];
    for (int i = t; i < total; i += 256) {
        const uint v = stage[i];
        const int b = ((int)(v >> 16) * NB) / NN;
        binned[gbase[b] + (i - ebase[b])] = v;   // absolute slot offset
    }
}

// ---------------- launch A: conv_wt blocks || bin_edges blocks --------------
__global__ __launch_bounds__(256) void prep_a(
    const float* __restrict__ W0, const float* __restrict__ W1,
    ushort* __restrict__ WT,
    const int* __restrict__ dst0, const int* __restrict__ dst1,
    const int* __restrict__ src0, const int* __restrict__ src1,
    int* __restrict__ gcur, uint* __restrict__ binned)
{
    __shared__ __align__(16) char smem[18944];
    const int bid = blockIdx.x;
    if (bid < 64) {
        conv_body(W0, W1, WT, bid);
    } else {
        bin_body(smem, dst0, dst1, src0, src1, gcur, binned, bid - 64);
    }
}

// ---------------- slot build: LDS-staged, coalesced output ------------------
// Per (set,bucket): build the whole 391-node x 64-slot window in LDS (51.6KB),
// scattering 2B writes into LDS (cheap) instead of global (R8's prep_b showed
// fine-grained global scatter caps the write path at ~1.1 TB/s via partial-
// line RMW). Output is then perfectly coalesced uint4 streams.
__global__ __launch_bounds__(256) void slot_build(
    const int* __restrict__ gcur, const uint* __restrict__ binned,
    int* __restrict__ cnt, ushort* __restrict__ slots)
{
    __shared__ ushort win[WINMAX * MAXDEG];   // 50048 B
    __shared__ int lcur[WINMAX];              // 1564 B
    const int bid = blockIdx.x;
    const int s = bid >> 7, b = bid & (NB - 1);
    const int nb0 = (b * NN + NB - 1) / NB;
    int nb1 = ((b + 1) * NN + NB - 1) / NB;
    if (nb1 > NN) nb1 = NN;
    const int nloc = nb1 - nb0;
    int fill = gcur[s * NB + b];
    if (fill > CAP) fill = CAP;
    const uint* bslot = binned + (size_t)(s * NB + b) * CAP;
    const int t = threadIdx.x;

    uint* wz = (uint*)win;
    for (int i = t; i < WINMAX * MAXDEG / 2; i += 256) wz[i] = 0;
    for (int i = t; i < nloc; i += 256) lcur[i] = 0;
    __syncthreads();
    for (int j = t; j < fill; j += 256) {
        const uint v = bslot[j];
        const int d = (int)(v >> 16) - nb0;
        const int p = atomicAdd(&lcur[d], 1);
        if (p < MAXDEG) win[d * MAXDEG + p] = (ushort)(v & 0xffffu);
    }
    __syncthreads();
    const uint4* wsrc = (const uint4*)win;
    uint4* wdst = (uint4*)(slots + ((size_t)s * NN + nb0) * MAXDEG);
    const int nq = nloc * (MAXDEG / 8);   // uint4 per window
    for (int i = t; i < nq; i += 256) wdst[i] = wsrc[i];
    for (int i = t; i < nloc; i += 256) {
        const int c = lcur[i];
        cnt[s * NN + nb0 + i] = c < MAXDEG ? c : MAXDEG;
    }
}

__device__ __forceinline__ float elu(float v) { return v > 0.f ? v : expm1f(v); }
__device__ __forceinline__ float2 bfpair(uint u) {
    union { uint i; float f; } lo, hi;
    lo.i = u << 16;
    hi.i = u & 0xffff0000u;
    return make_float2(lo.f, hi.f);
}

// ---------------- dual-relation fused softmax + aggregate -------------------
// One wave per dst node; lane owns dims (2*lane, 2*lane+1) of the output.
// deg <= 64 guaranteed by the slot build (clamped). 16-deep unrolled gather
// pipeline at VGPR ~32 (measured sweet spot; 32-deep fusion regressed).
__global__ __launch_bounds__(256) void aggregate_dual(
    const int* __restrict__ cnt0, const ushort* __restrict__ sl0,
    const int* __restrict__ cnt1, const ushort* __restrict__ sl1,
    const float2* __restrict__ el0, const float2* __restrict__ er0,
    const float2* __restrict__ el1, const float2* __restrict__ er1,
    const ushort* __restrict__ fg0, const ushort* __restrict__ fg1,
    const float* __restrict__ bias0, const float* __restrict__ bias1,
    float* __restrict__ outf, ushort* __restrict__ outbf, int obf)
{
    __shared__ uint soff[4][64];
    __shared__ float wts[4][2][64];
    const int wv = (blockIdx.x * 256 + threadIdx.x) >> 6;
    if (wv >= NN) return;
    const int lane = threadIdx.x & 63;
    const int wid = threadIdx.x >> 6;

    const int* cnts[2] = {cnt0, cnt1};
    const ushort* sls[2] = {sl0, sl1};
    const float2* els[2] = {el0, el1};
    const float2* ers[2] = {er0, er1};
    const ushort* fgs[2] = {fg0, fg1};
    const float* biases[2] = {bias0, bias1};

    float oacc0 = 0.f, oacc1 = 0.f;

#pragma unroll
    for (int rel = 0; rel < 2; rel++) {
        const int deg = cnts[rel][wv];   // <= MAXDEG by slot build
        const float2 erd = ers[rel][wv];
        float2 acc = make_float2(0.f, 0.f);

        uint sof = 0;
        float ex0 = 0.f, ex1 = 0.f;
        if (lane < deg) {
            const int s = sls[rel][(size_t)wv * MAXDEG + lane];
            const float2 e = els[rel][s];
            float e0 = e.x + erd.x, e1 = e.y + erd.y;
            e0 = e0 > 0.f ? e0 : 0.2f * e0;
            e1 = e1 > 0.f ? e1 : 0.2f * e1;
            ex0 = __expf(e0);
            ex1 = __expf(e1);
            sof = (uint)s << 8;
        }
        float den0 = ex0, den1 = ex1;
        for (int o = 32; o > 0; o >>= 1) {
            den0 += __shfl_xor(den0, o);
            den1 += __shfl_xor(den1, o);
        }
        const float inv0 = 1.0f / den0, inv1 = 1.0f / den1;
        soff[wid][lane] = sof;
        wts[wid][0][lane] = ex0 * inv0;   // 0 for lane >= deg
        wts[wid][1][lane] = ex1 * inv1;
        const char* fgb = (const char*)fgs[rel] + lane * 4;
        const float* wrow = wts[wid][lane >> 5];
        const uint* sorow = soff[wid];
        const int dp = (deg + 15) & ~15;   // pad slots: w=0, sof=0 (row 0)
        for (int tt = 0; tt < dp; tt += 16) {
            uint off[16];
            float wgt[16];
#pragma unroll
            for (int k = 0; k < 16; k++) {
                off[k] = sorow[tt + k];
                wgt[k] = wrow[tt + k];
            }
            uint u[16];
#pragma unroll
            for (int k = 0; k < 16; k++)
                u[k] = *(const uint*)(fgb + off[k]);
#pragma unroll
            for (int k = 0; k < 16; k++) {
                const float2 f = bfpair(u[k]);
                acc.x += f.x * wgt[k];
                acc.y += f.y * wgt[k];
            }
        }

        const float b0 = biases[rel][2 * lane], b1 = biases[rel][2 * lane + 1];
        oacc0 += elu(acc.x + b0);
        oacc1 += elu(acc.y + b1);
    }

    if (obf) {
        ushort tmp[2] = { f2bf(oacc0), f2bf(oacc1) };
        *(uint*)(outbf + (size_t)wv * DIM + 2 * lane) = *(const uint*)tmp;
    } else {
        float* op = outf + (size_t)wv * DIM + 2 * lane;
        op[0] = oacc0; op[1] = oacc1;
    }
}

extern "C" void kernel_launch(void* const* d_in, const int* in_sizes, int n_in,
                              void* d_out, int out_size, void* d_ws, size_t ws_size,
                              hipStream_t stream)
{
    const float* x   = (const float*)d_in[0];
    const float* W0  = (const float*)d_in[1];
    const float* al0 = (const float*)d_in[2];
    const float* ar0 = (const float*)d_in[3];
    const float* b0  = (const float*)d_in[4];
    const float* W1  = (const float*)d_in[5];
    const float* al1 = (const float*)d_in[6];
    const float* ar1 = (const float*)d_in[7];
    const float* b1  = (const float*)d_in[8];
    const int* src0 = (const int*)d_in[9];
    const int* dst0 = (const int*)d_in[10];
    const int* src1 = (const int*)d_in[11];
    const int* dst1 = (const int*)d_in[12];
    float* out = (float*)d_out;

    char* w = (char*)d_ws;
    auto alloc = [&](size_t bytes) {
        char* p = w; w += (bytes + 255) & ~(size_t)255; return p;
    };
    ushort* h1bf   = (ushort*)alloc((size_t)NN * DIM * 2);
    ushort* fg0    = (ushort*)alloc((size_t)NN * DIM * 2);
    ushort* fg1    = (ushort*)alloc((size_t)NN * DIM * 2);
    ushort* WT     = (ushort*)alloc((size_t)4 * DIM * DIM * 2);
    float*  elb    = (float*)alloc((size_t)8 * NN * 4);      // el0,er0,el1,er1
    int*    cnt    = (int*)alloc((size_t)4 * NN * 4);
    ushort* slots  = (ushort*)alloc((size_t)4 * NN * MAXDEG * 2);
    uint*   binned = (uint*)alloc((size_t)4 * NB * CAP * 4); // slotted
    int*    gcur   = (int*)alloc((size_t)4 * NB * 4);

    const int gblocks = (NN + 63) / 64;
    const int ablocks = (NN * 64 + 255) / 256;

    // ---- prep ----
    hipMemsetAsync(gcur, 0, (size_t)4 * NB * 4, stream);
    // conv_wt (64 blocks) || bin_edges (784 blocks)
    prep_a<<<64 + NBIN_BLOCKS, 256, 0, stream>>>(
        W0, W1, WT, dst0, dst1, src0, src1, gcur, binned);
    // per-(set,bucket) slot rows, LDS-staged
    slot_build<<<4 * NB, 256, 0, stream>>>(gcur, binned, cnt, slots);

    for (int L = 0; L < 2; L++) {
        gemm_dual<<<gblocks, 256, 0, stream>>>(
            L ? h1bf : nullptr, L ? nullptr : x,
            WT + (size_t)L * 2 * DIM * DIM,
            L ? al1 : al0, L ? ar1 : ar0,
            fg0, fg1, elb, NN, L ? 0 : 1);
        const float* b = L ? b1 : b0;
        const int es0 = L * 2, es1 = L * 2 + 1;
        float* el0p = elb;
        float* er0p = elb + (size_t)NN * 2;
        float* el1p = elb + (size_t)NN * 4;
        float* er1p = elb + (size_t)NN * 6;
        aggregate_dual<<<ablocks, 256, 0, stream>>>(
            cnt + (size_t)es0 * NN, slots + (size_t)es0 * NN * MAXDEG,
            cnt + (size_t)es1 * NN, slots + (size_t)es1 * NN * MAXDEG,
            (const float2*)el0p, (const float2*)er0p,
            (const float2*)el1p, (const float2*)er1p,
            fg0, fg1, b, b + DIM,
            L ? out : nullptr, L ? nullptr : h1bf, L ? 0 : 1);
    }
}

// Round 10
// 342.160 us; speedup vs baseline: 1.0361x; 1.0205x over previous
//
#include <hip/hip_runtime.h>

#define NN 50000
#define NE 800000
#define DIM 128
#define NB 128          // dst buckets for binned slot build
#define CH 4096         // edges per binning block
#define CAP 8192        // slots per bucket (mean 6250, sd 79 -> +24 sigma)
#define MAXDEG 64       // per-(set,dst) slot row; P(deg>64)~1e-21 for Poisson(16)
#define WINH 196        // nodes per half-window: ceil(ceil(NN/NB)/2)
#define BPSET ((NE + CH - 1) / CH)
#define NBIN_BLOCKS (4 * BPSET)

typedef unsigned int uint;
typedef unsigned short ushort;
typedef __attribute__((ext_vector_type(8))) short v8s;
typedef __attribute__((ext_vector_type(4))) float v4f;

__device__ __forceinline__ ushort f2bf(float f) {
    union { float f; uint i; } c; c.f = f;
    const uint r = (c.i + 0x7fffu + ((c.i >> 16) & 1u)) >> 16;
    return (ushort)r;
}

// ---------------- WT transpose body ----------------
// WT[m][n][k] = bf16(W[m][k][n]); m: 0,1 from W0, 2,3 from W1.
__device__ __forceinline__ void conv_body(
    const float* __restrict__ W0, const float* __restrict__ W1,
    ushort* __restrict__ WT, int bid)
{
    const int t = bid * 256 + threadIdx.x;
#pragma unroll
    for (int i = 0; i < 4; i++) {
        const int o = t * 4 + i;                    // 0 .. 65535
        const int m = o >> 14, rem = o & 16383;
        const int nrow = rem >> 7, k = rem & 127;
        const float* src = (m < 2) ? (W0 + (size_t)m * 16384)
                                   : (W1 + (size_t)(m - 2) * 16384);
        WT[o] = f2bf(src[k * 128 + nrow]);
    }
}

// ---------------- dual-relation MFMA GEMM body ----------------
// Block 256 = 4 waves; wave w: rows [b*64+16w,+16) x 128 cols, both relations.
// A loaded once (f32 path converts in-register). Epilogue: LDS-staged
// coalesced bf16 store + fused el/er reduction.
__device__ __forceinline__ void gemm_body(
    ushort (*tile)[136],
    const ushort* __restrict__ hbf, const float* __restrict__ xf,
    const ushort* __restrict__ WT,
    const float* __restrict__ al, const float* __restrict__ ar,
    ushort* __restrict__ fg0, ushort* __restrict__ fg1,
    float* __restrict__ elb, int n, int is_f32, int bid)
{
    const int tid = threadIdx.x;
    const int w = tid >> 6, lane = tid & 63;
    const int quad = lane >> 4, l16 = lane & 15;
    const int row0 = bid * 64 + w * 16;

    int arow = row0 + l16;
    if (arow >= n) arow = n - 1;   // clamp; OOB rows never stored

    v8s afr[4];
    if (is_f32) {
        const float* ap = xf + (size_t)arow * DIM + quad * 8;
#pragma unroll
        for (int kt = 0; kt < 4; kt++) {
            const float4 a0 = *(const float4*)(ap + kt * 32);
            const float4 a1 = *(const float4*)(ap + kt * 32 + 4);
            ushort tmp[8] = { f2bf(a0.x), f2bf(a0.y), f2bf(a0.z), f2bf(a0.w),
                              f2bf(a1.x), f2bf(a1.y), f2bf(a1.z), f2bf(a1.w) };
            afr[kt] = *(const v8s*)tmp;
        }
    } else {
        const ushort* ap = hbf + (size_t)arow * DIM + quad * 8;
#pragma unroll
        for (int kt = 0; kt < 4; kt++) afr[kt] = *(const v8s*)(ap + kt * 32);
    }

    for (int rel = 0; rel < 2; rel++) {
        const ushort* bp = WT + (size_t)rel * DIM * DIM + (size_t)l16 * DIM + quad * 8;
        v4f acc[8];
#pragma unroll
        for (int nt = 0; nt < 8; nt++) acc[nt] = (v4f)0.0f;
#pragma unroll
        for (int kt = 0; kt < 4; kt++) {
#pragma unroll
            for (int nt = 0; nt < 8; nt++) {
                const v8s b = *(const v8s*)(bp + (size_t)nt * 16 * DIM + kt * 32);
                acc[nt] = __builtin_amdgcn_mfma_f32_16x16x32_bf16(afr[kt], b, acc[nt], 0, 0, 0);
            }
        }

        // el/er: partial dot per lane, reduce across l16 within quad rows
        const float* alr = al + rel * DIM;
        const float* arr = ar + rel * DIM;
        float pel[4][2], per2[4][2];
#pragma unroll
        for (int r = 0; r < 4; r++)
            pel[r][0] = pel[r][1] = per2[r][0] = per2[r][1] = 0.f;
#pragma unroll
        for (int nt = 0; nt < 8; nt++) {
            const int col = nt * 16 + l16;
            const float av = alr[col], rv = arr[col];
            const int head = nt >> 2;
#pragma unroll
            for (int r = 0; r < 4; r++) {
                pel[r][head] += acc[nt][r] * av;
                per2[r][head] += acc[nt][r] * rv;
            }
        }
#pragma unroll
        for (int o = 1; o < 16; o <<= 1) {
#pragma unroll
            for (int r = 0; r < 4; r++) {
#pragma unroll
                for (int h = 0; h < 2; h++) {
                    pel[r][h] += __shfl_xor(pel[r][h], o);
                    per2[r][h] += __shfl_xor(per2[r][h], o);
                }
            }
        }
        float* elp = elb + (size_t)rel * NN * 4;
        float* erp = elp + (size_t)NN * 2;
        if (l16 == 0) {
#pragma unroll
            for (int r = 0; r < 4; r++) {
                const int row = row0 + quad * 4 + r;
                if (row < n) {
#pragma unroll
                    for (int h = 0; h < 2; h++) {
                        elp[row * 2 + h] = pel[r][h];
                        erp[row * 2 + h] = per2[r][h];
                    }
                }
            }
        }

        // coalesced bf16 store via LDS
        __syncthreads();   // prior rel's tile reads done
        const int lr0 = w * 16 + quad * 4;
#pragma unroll
        for (int nt = 0; nt < 8; nt++) {
            const int col = nt * 16 + l16;
#pragma unroll
            for (int r = 0; r < 4; r++)
                tile[lr0 + r][col] = f2bf(acc[nt][r]);
        }
        __syncthreads();
        ushort* fgr = rel ? fg1 : fg0;
        const int srow = tid >> 2, ch = tid & 3;   // 64 rows x 4 chunks of 32
        const int grow = bid * 64 + srow;
        if (grow < n) {
            const uint4* lp = (const uint4*)&tile[srow][ch * 32];
            uint4* gp = (uint4*)(fgr + (size_t)grow * DIM + ch * 32);
            gp[0] = lp[0];
            gp[1] = lp[1];
            gp[2] = lp[2];
            gp[3] = lp[3];
        }
    }
}

__global__ __launch_bounds__(256) void gemm_dual(
    const ushort* __restrict__ hbf, const float* __restrict__ xf,
    const ushort* __restrict__ WT,
    const float* __restrict__ al, const float* __restrict__ ar,
    ushort* __restrict__ fg0, ushort* __restrict__ fg1,
    float* __restrict__ elb, int n, int is_f32)
{
    __shared__ ushort tile[64][136];
    gemm_body(tile, hbf, xf, WT, al, ar, fg0, fg1, elb, n, is_f32, blockIdx.x);
}

// Pass A body: bin edges by dst bucket; payload packed (dst<<16)|src.
// gcur is a zero-initialized per-bucket fill counter; binned slot offsets are
// absolute ((s*NB+b)*CAP + fill).
__device__ __forceinline__ void bin_body(
    char* smem,
    const int* __restrict__ dst0, const int* __restrict__ dst1,
    const int* __restrict__ src0, const int* __restrict__ src1,
    int* __restrict__ gcur, uint* __restrict__ binned, int bid)
{
    int* hist  = (int*)smem;
    int* ebase = hist + NB;
    int* lcur  = ebase + NB;
    int* gbase = lcur + NB;
    int* sc    = gbase + NB;
    uint* stage = (uint*)(sc + NB);   // CH entries

    const int s = bid / BPSET, cb = bid - s * BPSET;
    const int* dstp = (s < 2) ? (dst0 + (size_t)s * NE) : (dst1 + (size_t)(s - 2) * NE);
    const int* srcp = (s < 2) ? (src0 + (size_t)s * NE) : (src1 + (size_t)(s - 2) * NE);
    const int e0 = cb * CH;
    const int t = threadIdx.x;

    if (t < NB) hist[t] = 0;
    __syncthreads();

    int myd[16], mys[16];
#pragma unroll
    for (int k = 0; k < 16; k++) {
        const int e = e0 + t + k * 256;
        if (e < NE) {
            const int d = dstp[e];
            myd[k] = d;
            mys[k] = srcp[e];
            atomicAdd(&hist[(d * NB) / NN], 1);
        } else myd[k] = -1;
    }
    __syncthreads();
    if (t < NB) sc[t] = hist[t];
    __syncthreads();
    for (int o = 1; o < NB; o <<= 1) {
        int tv = 0;
        if (t < NB && t >= o) tv = sc[t - o];
        __syncthreads();
        if (t < NB) sc[t] += tv;
        __syncthreads();
    }
    if (t < NB) {
        ebase[t] = sc[t] - hist[t];
        lcur[t]  = sc[t] - hist[t];
        gbase[t] = (s * NB + t) * CAP + atomicAdd(&gcur[s * NB + t], hist[t]);
    }
    __syncthreads();
#pragma unroll
    for (int k = 0; k < 16; k++) {
        if (myd[k] >= 0) {
            const int b = (myd[k] * NB) / NN;
            const int p = atomicAdd(&lcur[b], 1);
            stage[p] = ((uint)myd[k] << 16) | (uint)mys[k];
        }
    }
    __syncthreads();
    const int total = ebase[NB - 1] + hist[NB - 1];
    for (int i = t; i < total; i += 256) {
        const uint v = stage[i];
        const int b = ((int)(v >> 16) * NB) / NN;
        binned[gbase[b] + (i - ebase[b])] = v;   // absolute slot offset
    }
}

// ---------------- launch A: conv_wt blocks || bin_edges blocks --------------
__global__ __launch_bounds__(256) void prep_a(
    const float* __restrict__ W0, const float* __restrict__ W1,
    ushort* __restrict__ WT,
    const int* __restrict__ dst0, const int* __restrict__ dst1,
    const int* __restrict__ src0, const int* __restrict__ src1,
    int* __restrict__ gcur, uint* __restrict__ binned)
{
    __shared__ __align__(16) char smem[18944];
    const int bid = blockIdx.x;
    if (bid < 64) {
        conv_body(W0, W1, WT, bid);
    } else {
        bin_body(smem, dst0, dst1, src0, src1, gcur, binned, bid - 64);
    }
}

// ---------------- slot build body: LDS-staged half-window -------------------
// Per (set,bucket,half): build a <=196-node x 64-slot window in LDS (25.9KB),
// scattering 2B writes into LDS (cheap; global fine-grained scatter caps the
// write path at ~1.1 TB/s via partial-line RMW, measured R8), then write out
// as perfectly coalesced uint4 streams. Half-windows keep the LDS union with
// the co-launched gemm blocks at 25.9KB -> ~6 blocks/CU.
__device__ __forceinline__ void slot_body(
    char* smem, const int* __restrict__ gcur, const uint* __restrict__ binned,
    int* __restrict__ cnt, ushort* __restrict__ slots, int bid2)
{
    ushort* win = (ushort*)smem;            // WINH*64 = 25088 B
    int* lcur = (int*)(smem + WINH * MAXDEG * 2);   // 784 B
    const int s = bid2 >> 8, rem = bid2 & 255;
    const int b = rem >> 1, half = rem & 1;
    const int wb0 = (b * NN + NB - 1) / NB;
    int wb1 = ((b + 1) * NN + NB - 1) / NB;
    if (wb1 > NN) wb1 = NN;
    const int nb0 = wb0 + half * WINH;
    int nb1 = nb0 + WINH;
    if (nb1 > wb1) nb1 = wb1;
    if (nb0 >= nb1) return;
    const int nloc = nb1 - nb0;
    int fill = gcur[s * NB + b];
    if (fill > CAP) fill = CAP;
    const uint* bslot = binned + (size_t)(s * NB + b) * CAP;
    const int t = threadIdx.x;

    uint* wz = (uint*)win;
    for (int i = t; i < WINH * MAXDEG / 2; i += 256) wz[i] = 0;
    for (int i = t; i < nloc; i += 256) lcur[i] = 0;
    __syncthreads();
    for (int j = t; j < fill; j += 256) {
        const uint v = bslot[j];
        const int d = (int)(v >> 16) - nb0;
        if ((uint)d < (uint)nloc) {
            const int p = atomicAdd(&lcur[d], 1);
            if (p < MAXDEG) win[d * MAXDEG + p] = (ushort)(v & 0xffffu);
        }
    }
    __syncthreads();
    const uint4* wsrc = (const uint4*)win;
    uint4* wdst = (uint4*)(slots + ((size_t)s * NN + nb0) * MAXDEG);
    const int nq = nloc * (MAXDEG / 8);   // uint4 per window
    for (int i = t; i < nq; i += 256) wdst[i] = wsrc[i];
    for (int i = t; i < nloc; i += 256) {
        const int c = lcur[i];
        cnt[s * NN + nb0 + i] = c < MAXDEG ? c : MAXDEG;
    }
}

// ---------------- launch B: gemm layer-0 blocks || slot-build blocks --------
// Both depend only on prep_a; gemm is MFMA/stream-bound, slots LDS/L2-bound.
__global__ __launch_bounds__(256) void prep_b(
    const float* __restrict__ xf, const ushort* __restrict__ WT,
    const float* __restrict__ al, const float* __restrict__ ar,
    ushort* __restrict__ fg0, ushort* __restrict__ fg1,
    float* __restrict__ elb,
    const int* __restrict__ gcur, const uint* __restrict__ binned,
    int* __restrict__ cnt, ushort* __restrict__ slots, int gblocks)
{
    __shared__ __align__(16) char smem[25888];  // max(gemm 17408, slot 25872)
    const int bid = blockIdx.x;
    if (bid < gblocks) {
        gemm_body((ushort(*)[136])smem, nullptr, xf, WT, al, ar,
                  fg0, fg1, elb, NN, 1, bid);
    } else {
        slot_body(smem, gcur, binned, cnt, slots, bid - gblocks);
    }
}

__device__ __forceinline__ float elu(float v) { return v > 0.f ? v : expm1f(v); }
__device__ __forceinline__ float2 bfpair(uint u) {
    union { uint i; float f; } lo, hi;
    lo.i = u << 16;
    hi.i = u & 0xffff0000u;
    return make_float2(lo.f, hi.f);
}

// ---------------- dual-relation fused softmax + aggregate -------------------
// One wave per dst node; lane owns dims (2*lane, 2*lane+1) of the output.
// deg <= 64 guaranteed by the slot build (clamped). 16-deep unrolled gather
// pipeline at VGPR ~32 (measured sweet spot; 32-deep fusion regressed).
__global__ __launch_bounds__(256) void aggregate_dual(
    const int* __restrict__ cnt0, const ushort* __restrict__ sl0,
    const int* __restrict__ cnt1, const ushort* __restrict__ sl1,
    const float2* __restrict__ el0, const float2* __restrict__ er0,
    const float2* __restrict__ el1, const float2* __restrict__ er1,
    const ushort* __restrict__ fg0, const ushort* __restrict__ fg1,
    const float* __restrict__ bias0, const float* __restrict__ bias1,
    float* __restrict__ outf, ushort* __restrict__ outbf, int obf)
{
    __shared__ uint soff[4][64];
    __shared__ float wts[4][2][64];
    const int wv = (blockIdx.x * 256 + threadIdx.x) >> 6;
    if (wv >= NN) return;
    const int lane = threadIdx.x & 63;
    const int wid = threadIdx.x >> 6;

    const int* cnts[2] = {cnt0, cnt1};
    const ushort* sls[2] = {sl0, sl1};
    const float2* els[2] = {el0, el1};
    const float2* ers[2] = {er0, er1};
    const ushort* fgs[2] = {fg0, fg1};
    const float* biases[2] = {bias0, bias1};

    float oacc0 = 0.f, oacc1 = 0.f;

#pragma unroll
    for (int rel = 0; rel < 2; rel++) {
        const int deg = cnts[rel][wv];   // <= MAXDEG by slot build
        const float2 erd = ers[rel][wv];
        float2 acc = make_float2(0.f, 0.f);

        uint sof = 0;
        float ex0 = 0.f, ex1 = 0.f;
        if (lane < deg) {
            const int s = sls[rel][(size_t)wv * MAXDEG + lane];
            const float2 e = els[rel][s];
            float e0 = e.x + erd.x, e1 = e.y + erd.y;
            e0 = e0 > 0.f ? e0 : 0.2f * e0;
            e1 = e1 > 0.f ? e1 : 0.2f * e1;
            ex0 = __expf(e0);
            ex1 = __expf(e1);
            sof = (uint)s << 8;
        }
        float den0 = ex0, den1 = ex1;
        for (int o = 32; o > 0; o >>= 1) {
            den0 += __shfl_xor(den0, o);
            den1 += __shfl_xor(den1, o);
        }
        const float inv0 = 1.0f / den0, inv1 = 1.0f / den1;
        soff[wid][lane] = sof;
        wts[wid][0][lane] = ex0 * inv0;   // 0 for lane >= deg
        wts[wid][1][lane] = ex1 * inv1;
        const char* fgb = (const char*)fgs[rel] + lane * 4;
        const float* wrow = wts[wid][lane >> 5];
        const uint* sorow = soff[wid];
        const int dp = (deg + 15) & ~15;   // pad slots: w=0, sof=0 (row 0)
        for (int tt = 0; tt < dp; tt += 16) {
            uint off[16];
            float wgt[16];
#pragma unroll
            for (int k = 0; k < 16; k++) {
                off[k] = sorow[tt + k];
                wgt[k] = wrow[tt + k];
            }
            uint u[16];
#pragma unroll
            for (int k = 0; k < 16; k++)
                u[k] = *(const uint*)(fgb + off[k]);
#pragma unroll
            for (int k = 0; k < 16; k++) {
                const float2 f = bfpair(u[k]);
                acc.x += f.x * wgt[k];
                acc.y += f.y * wgt[k];
            }
        }

        const float b0 = biases[rel][2 * lane], b1 = biases[rel][2 * lane + 1];
        oacc0 += elu(acc.x + b0);
        oacc1 += elu(acc.y + b1);
    }

    if (obf) {
        ushort tmp[2] = { f2bf(oacc0), f2bf(oacc1) };
        *(uint*)(outbf + (size_t)wv * DIM + 2 * lane) = *(const uint*)tmp;
    } else {
        float* op = outf + (size_t)wv * DIM + 2 * lane;
        op[0] = oacc0; op[1] = oacc1;
    }
}

extern "C" void kernel_launch(void* const* d_in, const int* in_sizes, int n_in,
                              void* d_out, int out_size, void* d_ws, size_t ws_size,
                              hipStream_t stream)
{
    const float* x   = (const float*)d_in[0];
    const float* W0  = (const float*)d_in[1];
    const float* al0 = (const float*)d_in[2];
    const float* ar0 = (const float*)d_in[3];
    const float* b0  = (const float*)d_in[4];
    const float* W1  = (const float*)d_in[5];
    const float* al1 = (const float*)d_in[6];
    const float* ar1 = (const float*)d_in[7];
    const float* b1  = (const float*)d_in[8];
    const int* src0 = (const int*)d_in[9];
    const int* dst0 = (const int*)d_in[10];
    const int* src1 = (const int*)d_in[11];
    const int* dst1 = (const int*)d_in[12];
    float* out = (float*)d_out;

    char* w = (char*)d_ws;
    auto alloc = [&](size_t bytes) {
        char* p = w; w += (bytes + 255) & ~(size_t)255; return p;
    };
    ushort* h1bf   = (ushort*)alloc((size_t)NN * DIM * 2);
    ushort* fg0    = (ushort*)alloc((size_t)NN * DIM * 2);
    ushort* fg1    = (ushort*)alloc((size_t)NN * DIM * 2);
    ushort* WT     = (ushort*)alloc((size_t)4 * DIM * DIM * 2);
    float*  elb    = (float*)alloc((size_t)8 * NN * 4);      // el0,er0,el1,er1
    int*    cnt    = (int*)alloc((size_t)4 * NN * 4);
    ushort* slots  = (ushort*)alloc((size_t)4 * NN * MAXDEG * 2);
    uint*   binned = (uint*)alloc((size_t)4 * NB * CAP * 4); // slotted
    int*    gcur   = (int*)alloc((size_t)4 * NB * 4);

    const int gblocks = (NN + 63) / 64;
    const int ablocks = (NN * 64 + 255) / 256;

    // ---- prep ----
    hipMemsetAsync(gcur, 0, (size_t)4 * NB * 4, stream);
    // conv_wt (64 blocks) || bin_edges (784 blocks)
    prep_a<<<64 + NBIN_BLOCKS, 256, 0, stream>>>(
        W0, W1, WT, dst0, dst1, src0, src1, gcur, binned);
    // gemm layer-0 (782 blocks) || slot half-windows (1024 blocks)
    prep_b<<<gblocks + 4 * NB * 2, 256, 0, stream>>>(
        x, WT, al0, ar0, fg0, fg1, elb, gcur, binned, cnt, slots, gblocks);

    for (int L = 0; L < 2; L++) {
        if (L) {
            gemm_dual<<<gblocks, 256, 0, stream>>>(
                h1bf, nullptr, WT + (size_t)2 * DIM * DIM, al1, ar1,
                fg0, fg1, elb, NN, 0);
        }
        const float* b = L ? b1 : b0;
        const int es0 = L * 2, es1 = L * 2 + 1;
        float* el0p = elb;
        float* er0p = elb + (size_t)NN * 2;
        float* el1p = elb + (size_t)NN * 4;
        float* er1p = elb + (size_t)NN * 6;
        aggregate_dual<<<ablocks, 256, 0, stream>>>(
            cnt + (size_t)es0 * NN, slots + (size_t)es0 * NN * MAXDEG,
            cnt + (size_t)es1 * NN, slots + (size_t)es1 * NN * MAXDEG,
            (const float2*)el0p, (const float2*)er0p,
            (const float2*)el1p, (const float2*)er1p,
            fg0, fg1, b, b + DIM,
            L ? out : nullptr, L ? nullptr : h1bf, L ? 0 : 1);
    }
}

// Round 11
// 338.870 us; speedup vs baseline: 1.0461x; 1.0097x over previous
//
#include <hip/hip_runtime.h>

#define NN 50000
#define NE 800000
#define DIM 128
#define NB 128          // dst buckets for binned slot build
#define CH 2048         // edges per binning block (halved: 2x bin TLP)
#define CAP 8192        // slots per bucket (mean 6250, sd 79 -> +24 sigma)
#define MAXDEG 64       // per-(set,dst) slot row; P(deg>64)~1e-21 for Poisson(16)
#define WINH 196        // nodes per half-window: ceil(ceil(NN/NB)/2)
#define BPSET ((NE + CH - 1) / CH)
#define NBIN_BLOCKS (4 * BPSET)
#define GRBLK ((NN + 63) / 64)      // 782 row-blocks
#define NGEMM (2 * GRBLK)           // rel-split gemm blocks

typedef unsigned int uint;
typedef unsigned short ushort;
typedef __attribute__((ext_vector_type(8))) short v8s;
typedef __attribute__((ext_vector_type(4))) float v4f;

__device__ __forceinline__ ushort f2bf(float f) {
    union { float f; uint i; } c; c.f = f;
    const uint r = (c.i + 0x7fffu + ((c.i >> 16) & 1u)) >> 16;
    return (ushort)r;
}

// ---------------- WT transpose body ----------------
// WT[m][n][k] = bf16(W[m][k][n]); m: 0,1 from W0, 2,3 from W1.
__device__ __forceinline__ void conv_body(
    const float* __restrict__ W0, const float* __restrict__ W1,
    ushort* __restrict__ WT, int bid)
{
    const int t = bid * 256 + threadIdx.x;
#pragma unroll
    for (int i = 0; i < 4; i++) {
        const int o = t * 4 + i;                    // 0 .. 65535
        const int m = o >> 14, rem = o & 16383;
        const int nrow = rem >> 7, k = rem & 127;
        const float* src = (m < 2) ? (W0 + (size_t)m * 16384)
                                   : (W1 + (size_t)(m - 2) * 16384);
        WT[o] = f2bf(src[k * 128 + nrow]);
    }
}

// ---------------- single-relation MFMA GEMM body ----------------
// Rel-split for 2x TLP: mid kernels are latency-bound at ~3 waves/SIMD
// (R8: prep_b occupancy 23%); one rel per block doubles wave count and
// halves each block's dependent chain. A-frag reads duplicate across the
// two rel-blocks of a row (L2/L3-absorbed).
// Block 256 = 4 waves; wave w: rows [rb*64+16w,+16) x 128 cols, one rel.
__device__ __forceinline__ void gemm_rel_body(
    ushort (*tile)[136],
    const ushort* __restrict__ hbf, const float* __restrict__ xf,
    const ushort* __restrict__ WTr,   // rel-offset weight base
    const float* __restrict__ alr, const float* __restrict__ arr,
    ushort* __restrict__ fgr, float* __restrict__ elp, float* __restrict__ erp,
    int n, int is_f32, int rb)
{
    const int tid = threadIdx.x;
    const int w = tid >> 6, lane = tid & 63;
    const int quad = lane >> 4, l16 = lane & 15;
    const int row0 = rb * 64 + w * 16;

    int arow = row0 + l16;
    if (arow >= n) arow = n - 1;   // clamp; OOB rows never stored

    v8s afr[4];
    if (is_f32) {
        const float* ap = xf + (size_t)arow * DIM + quad * 8;
#pragma unroll
        for (int kt = 0; kt < 4; kt++) {
            const float4 a0 = *(const float4*)(ap + kt * 32);
            const float4 a1 = *(const float4*)(ap + kt * 32 + 4);
            ushort tmp[8] = { f2bf(a0.x), f2bf(a0.y), f2bf(a0.z), f2bf(a0.w),
                              f2bf(a1.x), f2bf(a1.y), f2bf(a1.z), f2bf(a1.w) };
            afr[kt] = *(const v8s*)tmp;
        }
    } else {
        const ushort* ap = hbf + (size_t)arow * DIM + quad * 8;
#pragma unroll
        for (int kt = 0; kt < 4; kt++) afr[kt] = *(const v8s*)(ap + kt * 32);
    }

    const ushort* bp = WTr + (size_t)l16 * DIM + quad * 8;
    v4f acc[8];
#pragma unroll
    for (int nt = 0; nt < 8; nt++) acc[nt] = (v4f)0.0f;
#pragma unroll
    for (int kt = 0; kt < 4; kt++) {
#pragma unroll
        for (int nt = 0; nt < 8; nt++) {
            const v8s b = *(const v8s*)(bp + (size_t)nt * 16 * DIM + kt * 32);
            acc[nt] = __builtin_amdgcn_mfma_f32_16x16x32_bf16(afr[kt], b, acc[nt], 0, 0, 0);
        }
    }

    // el/er: partial dot per lane, reduce across l16 within quad rows
    float pel[4][2], per2[4][2];
#pragma unroll
    for (int r = 0; r < 4; r++)
        pel[r][0] = pel[r][1] = per2[r][0] = per2[r][1] = 0.f;
#pragma unroll
    for (int nt = 0; nt < 8; nt++) {
        const int col = nt * 16 + l16;
        const float av = alr[col], rv = arr[col];
        const int head = nt >> 2;
#pragma unroll
        for (int r = 0; r < 4; r++) {
            pel[r][head] += acc[nt][r] * av;
            per2[r][head] += acc[nt][r] * rv;
        }
    }
#pragma unroll
    for (int o = 1; o < 16; o <<= 1) {
#pragma unroll
        for (int r = 0; r < 4; r++) {
#pragma unroll
            for (int h = 0; h < 2; h++) {
                pel[r][h] += __shfl_xor(pel[r][h], o);
                per2[r][h] += __shfl_xor(per2[r][h], o);
            }
        }
    }
    if (l16 == 0) {
#pragma unroll
        for (int r = 0; r < 4; r++) {
            const int row = row0 + quad * 4 + r;
            if (row < n) {
#pragma unroll
                for (int h = 0; h < 2; h++) {
                    elp[row * 2 + h] = pel[r][h];
                    erp[row * 2 + h] = per2[r][h];
                }
            }
        }
    }

    // coalesced bf16 store via LDS
    const int lr0 = w * 16 + quad * 4;
#pragma unroll
    for (int nt = 0; nt < 8; nt++) {
        const int col = nt * 16 + l16;
#pragma unroll
        for (int r = 0; r < 4; r++)
            tile[lr0 + r][col] = f2bf(acc[nt][r]);
    }
    __syncthreads();
    const int srow = tid >> 2, ch = tid & 3;   // 64 rows x 4 chunks of 32
    const int grow = rb * 64 + srow;
    if (grow < n) {
        const uint4* lp = (const uint4*)&tile[srow][ch * 32];
        uint4* gp = (uint4*)(fgr + (size_t)grow * DIM + ch * 32);
        gp[0] = lp[0];
        gp[1] = lp[1];
        gp[2] = lp[2];
        gp[3] = lp[3];
    }
}

__global__ __launch_bounds__(256) void gemm_rel(
    const ushort* __restrict__ hbf, const float* __restrict__ xf,
    const ushort* __restrict__ WT,   // layer base (2 rels)
    const float* __restrict__ al, const float* __restrict__ ar,
    ushort* __restrict__ fg0, ushort* __restrict__ fg1,
    float* __restrict__ elb, int n, int is_f32)
{
    __shared__ ushort tile[64][136];
    const int rel = blockIdx.x & 1, rb = blockIdx.x >> 1;
    float* elp = elb + (size_t)rel * NN * 4;
    gemm_rel_body(tile, hbf, xf, WT + (size_t)rel * DIM * DIM,
                  al + rel * DIM, ar + rel * DIM,
                  rel ? fg1 : fg0, elp, elp + (size_t)NN * 2,
                  n, is_f32, rb);
}

// Pass A body: bin edges by dst bucket; payload packed (dst<<16)|src.
// gcur is a zero-initialized per-bucket fill counter; binned slot offsets are
// absolute ((s*NB+b)*CAP + fill).
__device__ __forceinline__ void bin_body(
    char* smem,
    const int* __restrict__ dst0, const int* __restrict__ dst1,
    const int* __restrict__ src0, const int* __restrict__ src1,
    int* __restrict__ gcur, uint* __restrict__ binned, int bid)
{
    int* hist  = (int*)smem;
    int* ebase = hist + NB;
    int* lcur  = ebase + NB;
    int* gbase = lcur + NB;
    int* sc    = gbase + NB;
    uint* stage = (uint*)(sc + NB);   // CH entries

    const int s = bid / BPSET, cb = bid - s * BPSET;
    const int* dstp = (s < 2) ? (dst0 + (size_t)s * NE) : (dst1 + (size_t)(s - 2) * NE);
    const int* srcp = (s < 2) ? (src0 + (size_t)s * NE) : (src1 + (size_t)(s - 2) * NE);
    const int e0 = cb * CH;
    const int t = threadIdx.x;

    if (t < NB) hist[t] = 0;
    __syncthreads();

    int myd[8], mys[8];
#pragma unroll
    for (int k = 0; k < 8; k++) {
        const int e = e0 + t + k * 256;
        if (e < NE) {
            const int d = dstp[e];
            myd[k] = d;
            mys[k] = srcp[e];
            atomicAdd(&hist[(d * NB) / NN], 1);
        } else myd[k] = -1;
    }
    __syncthreads();
    if (t < NB) sc[t] = hist[t];
    __syncthreads();
    for (int o = 1; o < NB; o <<= 1) {
        int tv = 0;
        if (t < NB && t >= o) tv = sc[t - o];
        __syncthreads();
        if (t < NB) sc[t] += tv;
        __syncthreads();
    }
    if (t < NB) {
        ebase[t] = sc[t] - hist[t];
        lcur[t]  = sc[t] - hist[t];
        gbase[t] = (s * NB + t) * CAP + atomicAdd(&gcur[s * NB + t], hist[t]);
    }
    __syncthreads();
#pragma unroll
    for (int k = 0; k < 8; k++) {
        if (myd[k] >= 0) {
            const int b = (myd[k] * NB) / NN;
            const int p = atomicAdd(&lcur[b], 1);
            stage[p] = ((uint)myd[k] << 16) | (uint)mys[k];
        }
    }
    __syncthreads();
    const int total = ebase[NB - 1] + hist[NB - 1];
    for (int i = t; i < total; i += 256) {
        const uint v = stage[i];
        const int b = ((int)(v >> 16) * NB) / NN;
        binned[gbase[b] + (i - ebase[b])] = v;   // absolute slot offset
    }
}

// ---------------- launch A: conv_wt blocks || bin_edges blocks --------------
__global__ __launch_bounds__(256) void prep_a(
    const float* __restrict__ W0, const float* __restrict__ W1,
    ushort* __restrict__ WT,
    const int* __restrict__ dst0, const int* __restrict__ dst1,
    const int* __restrict__ src0, const int* __restrict__ src1,
    int* __restrict__ gcur, uint* __restrict__ binned)
{
    __shared__ __align__(16) char smem[10752];  // bin: 5*NB*4 + CH*4
    const int bid = blockIdx.x;
    if (bid < 64) {
        conv_body(W0, W1, WT, bid);
    } else {
        bin_body(smem, dst0, dst1, src0, src1, gcur, binned, bid - 64);
    }
}

// ---------------- slot build body: LDS-staged half-window -------------------
// Per (set,bucket,half): build a <=196-node x 64-slot window in LDS (25.9KB),
// scattering 2B writes into LDS (cheap; global fine-grained scatter caps the
// write path at ~1.1 TB/s via partial-line RMW, measured R8), then write out
// as perfectly coalesced uint4 streams.
__device__ __forceinline__ void slot_body(
    char* smem, const int* __restrict__ gcur, const uint* __restrict__ binned,
    int* __restrict__ cnt, ushort* __restrict__ slots, int bid2)
{
    ushort* win = (ushort*)smem;            // WINH*64 = 25088 B
    int* lcur = (int*)(smem + WINH * MAXDEG * 2);   // 784 B
    const int s = bid2 >> 8, rem = bid2 & 255;
    const int b = rem >> 1, half = rem & 1;
    const int wb0 = (b * NN + NB - 1) / NB;
    int wb1 = ((b + 1) * NN + NB - 1) / NB;
    if (wb1 > NN) wb1 = NN;
    const int nb0 = wb0 + half * WINH;
    int nb1 = nb0 + WINH;
    if (nb1 > wb1) nb1 = wb1;
    if (nb0 >= nb1) return;
    const int nloc = nb1 - nb0;
    int fill = gcur[s * NB + b];
    if (fill > CAP) fill = CAP;
    const uint* bslot = binned + (size_t)(s * NB + b) * CAP;
    const int t = threadIdx.x;

    uint* wz = (uint*)win;
    for (int i = t; i < WINH * MAXDEG / 2; i += 256) wz[i] = 0;
    for (int i = t; i < nloc; i += 256) lcur[i] = 0;
    __syncthreads();
    for (int j = t; j < fill; j += 256) {
        const uint v = bslot[j];
        const int d = (int)(v >> 16) - nb0;
        if ((uint)d < (uint)nloc) {
            const int p = atomicAdd(&lcur[d], 1);
            if (p < MAXDEG) win[d * MAXDEG + p] = (ushort)(v & 0xffffu);
        }
    }
    __syncthreads();
    const uint4* wsrc = (const uint4*)win;
    uint4* wdst = (uint4*)(slots + ((size_t)s * NN + nb0) * MAXDEG);
    const int nq = nloc * (MAXDEG / 8);   // uint4 per window
    for (int i = t; i < nq; i += 256) wdst[i] = wsrc[i];
    for (int i = t; i < nloc; i += 256) {
        const int c = lcur[i];
        cnt[s * NN + nb0 + i] = c < MAXDEG ? c : MAXDEG;
    }
}

// ---------------- launch B: gemm layer-0 rel-blocks || slot-build blocks ----
// Both depend only on prep_a; gemm is MFMA/stream-bound, slots LDS/L2-bound.
__global__ __launch_bounds__(256) void prep_b(
    const float* __restrict__ xf, const ushort* __restrict__ WT,
    const float* __restrict__ al, const float* __restrict__ ar,
    ushort* __restrict__ fg0, ushort* __restrict__ fg1,
    float* __restrict__ elb,
    const int* __restrict__ gcur, const uint* __restrict__ binned,
    int* __restrict__ cnt, ushort* __restrict__ slots)
{
    __shared__ __align__(16) char smem[25888];  // max(gemm 17408, slot 25872)
    const int bid = blockIdx.x;
    if (bid < NGEMM) {
        const int rel = bid & 1, rb = bid >> 1;
        float* elp = elb + (size_t)rel * NN * 4;
        gemm_rel_body((ushort(*)[136])smem, nullptr, xf,
                      WT + (size_t)rel * DIM * DIM,
                      al + rel * DIM, ar + rel * DIM,
                      rel ? fg1 : fg0, elp, elp + (size_t)NN * 2,
                      NN, 1, rb);
    } else {
        slot_body(smem, gcur, binned, cnt, slots, bid - NGEMM);
    }
}

__device__ __forceinline__ float elu(float v) { return v > 0.f ? v : expm1f(v); }
__device__ __forceinline__ float2 bfpair(uint u) {
    union { uint i; float f; } lo, hi;
    lo.i = u << 16;
    hi.i = u & 0xffff0000u;
    return make_float2(lo.f, hi.f);
}

// ---------------- dual-relation fused softmax + aggregate -------------------
// One wave per dst node; lane owns dims (2*lane, 2*lane+1) of the output.
// deg <= 64 guaranteed by the slot build (clamped). 16-deep unrolled gather
// pipeline at VGPR ~32 (measured sweet spot; 32-deep fusion regressed).
__global__ __launch_bounds__(256) void aggregate_dual(
    const int* __restrict__ cnt0, const ushort* __restrict__ sl0,
    const int* __restrict__ cnt1, const ushort* __restrict__ sl1,
    const float2* __restrict__ el0, const float2* __restrict__ er0,
    const float2* __restrict__ el1, const float2* __restrict__ er1,
    const ushort* __restrict__ fg0, const ushort* __restrict__ fg1,
    const float* __restrict__ bias0, const float* __restrict__ bias1,
    float* __restrict__ outf, ushort* __restrict__ outbf, int obf)
{
    __shared__ uint soff[4][64];
    __shared__ float wts[4][2][64];
    const int wv = (blockIdx.x * 256 + threadIdx.x) >> 6;
    if (wv >= NN) return;
    const int lane = threadIdx.x & 63;
    const int wid = threadIdx.x >> 6;

    const int* cnts[2] = {cnt0, cnt1};
    const ushort* sls[2] = {sl0, sl1};
    const float2* els[2] = {el0, el1};
    const float2* ers[2] = {er0, er1};
    const ushort* fgs[2] = {fg0, fg1};
    const float* biases[2] = {bias0, bias1};

    float oacc0 = 0.f, oacc1 = 0.f;

#pragma unroll
    for (int rel = 0; rel < 2; rel++) {
        const int deg = cnts[rel][wv];   // <= MAXDEG by slot build
        const float2 erd = ers[rel][wv];
        float2 acc = make_float2(0.f, 0.f);

        uint sof = 0;
        float ex0 = 0.f, ex1 = 0.f;
        if (lane < deg) {
            const int s = sls[rel][(size_t)wv * MAXDEG + lane];
            const float2 e = els[rel][s];
            float e0 = e.x + erd.x, e1 = e.y + erd.y;
            e0 = e0 > 0.f ? e0 : 0.2f * e0;
            e1 = e1 > 0.f ? e1 : 0.2f * e1;
            ex0 = __expf(e0);
            ex1 = __expf(e1);
            sof = (uint)s << 8;
        }
        float den0 = ex0, den1 = ex1;
        for (int o = 32; o > 0; o >>= 1) {
            den0 += __shfl_xor(den0, o);
            den1 += __shfl_xor(den1, o);
        }
        const float inv0 = 1.0f / den0, inv1 = 1.0f / den1;
        soff[wid][lane] = sof;
        wts[wid][0][lane] = ex0 * inv0;   // 0 for lane >= deg
        wts[wid][1][lane] = ex1 * inv1;
        const char* fgb = (const char*)fgs[rel] + lane * 4;
        const float* wrow = wts[wid][lane >> 5];
        const uint* sorow = soff[wid];
        const int dp = (deg + 15) & ~15;   // pad slots: w=0, sof=0 (row 0)
        for (int tt = 0; tt < dp; tt += 16) {
            uint off[16];
            float wgt[16];
#pragma unroll
            for (int k = 0; k < 16; k++) {
                off[k] = sorow[tt + k];
                wgt[k] = wrow[tt + k];
            }
            uint u[16];
#pragma unroll
            for (int k = 0; k < 16; k++)
                u[k] = *(const uint*)(fgb + off[k]);
#pragma unroll
            for (int k = 0; k < 16; k++) {
                const float2 f = bfpair(u[k]);
                acc.x += f.x * wgt[k];
                acc.y += f.y * wgt[k];
            }
        }

        const float b0 = biases[rel][2 * lane], b1 = biases[rel][2 * lane + 1];
        oacc0 += elu(acc.x + b0);
        oacc1 += elu(acc.y + b1);
    }

    if (obf) {
        ushort tmp[2] = { f2bf(oacc0), f2bf(oacc1) };
        *(uint*)(outbf + (size_t)wv * DIM + 2 * lane) = *(const uint*)tmp;
    } else {
        float* op = outf + (size_t)wv * DIM + 2 * lane;
        op[0] = oacc0; op[1] = oacc1;
    }
}

extern "C" void kernel_launch(void* const* d_in, const int* in_sizes, int n_in,
                              void* d_out, int out_size, void* d_ws, size_t ws_size,
                              hipStream_t stream)
{
    const float* x   = (const float*)d_in[0];
    const float* W0  = (const float*)d_in[1];
    const float* al0 = (const float*)d_in[2];
    const float* ar0 = (const float*)d_in[3];
    const float* b0  = (const float*)d_in[4];
    const float* W1  = (const float*)d_in[5];
    const float* al1 = (const float*)d_in[6];
    const float* ar1 = (const float*)d_in[7];
    const float* b1  = (const float*)d_in[8];
    const int* src0 = (const int*)d_in[9];
    const int* dst0 = (const int*)d_in[10];
    const int* src1 = (const int*)d_in[11];
    const int* dst1 = (const int*)d_in[12];
    float* out = (float*)d_out;

    char* w = (char*)d_ws;
    auto alloc = [&](size_t bytes) {
        char* p = w; w += (bytes + 255) & ~(size_t)255; return p;
    };
    ushort* h1bf   = (ushort*)alloc((size_t)NN * DIM * 2);
    ushort* fg0    = (ushort*)alloc((size_t)NN * DIM * 2);
    ushort* fg1    = (ushort*)alloc((size_t)NN * DIM * 2);
    ushort* WT     = (ushort*)alloc((size_t)4 * DIM * DIM * 2);
    float*  elb    = (float*)alloc((size_t)8 * NN * 4);      // el0,er0,el1,er1
    int*    cnt    = (int*)alloc((size_t)4 * NN * 4);
    ushort* slots  = (ushort*)alloc((size_t)4 * NN * MAXDEG * 2);
    uint*   binned = (uint*)alloc((size_t)4 * NB * CAP * 4); // slotted
    int*    gcur   = (int*)alloc((size_t)4 * NB * 4);

    const int ablocks = (NN * 64 + 255) / 256;

    // ---- prep ----
    hipMemsetAsync(gcur, 0, (size_t)4 * NB * 4, stream);
    // conv_wt (64 blocks) || bin_edges (1564 blocks)
    prep_a<<<64 + NBIN_BLOCKS, 256, 0, stream>>>(
        W0, W1, WT, dst0, dst1, src0, src1, gcur, binned);
    // gemm layer-0 rel-blocks (1564) || slot half-windows (1024)
    prep_b<<<NGEMM + 4 * NB * 2, 256, 0, stream>>>(
        x, WT, al0, ar0, fg0, fg1, elb, gcur, binned, cnt, slots);

    for (int L = 0; L < 2; L++) {
        if (L) {
            gemm_rel<<<NGEMM, 256, 0, stream>>>(
                h1bf, nullptr, WT + (size_t)2 * DIM * DIM, al1, ar1,
                fg0, fg1, elb, NN, 0);
        }
        const float* b = L ? b1 : b0;
        const int es0 = L * 2, es1 = L * 2 + 1;
        float* el0p = elb;
        float* er0p = elb + (size_t)NN * 2;
        float* el1p = elb + (size_t)NN * 4;
        float* er1p = elb + (size_t)NN * 6;
        aggregate_dual<<<ablocks, 256, 0, stream>>>(
            cnt + (size_t)es0 * NN, slots + (size_t)es0 * NN * MAXDEG,
            cnt + (size_t)es1 * NN, slots + (size_t)es1 * NN * MAXDEG,
            (const float2*)el0p, (const float2*)er0p,
            (const float2*)el1p, (const float2*)er1p,
            fg0, fg1, b, b + DIM,
            L ? out : nullptr, L ? nullptr : h1bf, L ? 0 : 1);
    }
}